// Round 4
// baseline (558.110 us; speedup 1.0000x reference)
//
#include <hip/hip_runtime.h>
#include <hip/hip_bf16.h>

#define B_ 256
#define D_ 511
#define H_ 5120
#define NTOT (D_ * D_)   // 261121

typedef __attribute__((ext_vector_type(4))) float floatx4;
typedef __attribute__((ext_vector_type(8))) short short8;

union I4S8 { int4 i4; short8 s8; };

__device__ __forceinline__ unsigned short f2bf(float v) {
    __hip_bfloat16 h = __float2bfloat16(v);
    return __builtin_bit_cast(unsigned short, h);
}

// byte offset of a 16B chunk in a swizzled 64x64-bf16 LDS tile (row stride 128B)
__device__ __forceinline__ int sw_off(int row, int chunk) {
    return row * 128 + ((chunk ^ (row & 7)) * 16);
}

// ============ GEMM1 (MFMA): h[256][5120] = relu(theta @ w1^T + b1) ============
// theta [256][511] fp32, w1 [5120][511] fp32 (both K-contiguous). K padded to 512.
__global__ __launch_bounds__(256) void gemm1_mfma(
    const float* __restrict__ A, const float* __restrict__ W,
    const float* __restrict__ bias, __hip_bfloat16* __restrict__ Hout)
{
    __shared__ char lds[16384];
    char* Ab = lds;
    char* Bb = lds + 8192;
    const int t = threadIdx.x;
    const int m0 = blockIdx.y * 64;
    const int n0 = blockIdx.x * 64;
    const int lane = t & 63, wave = t >> 6;
    const int wm = (wave & 1) * 32, wn = (wave >> 1) * 32;
    const int lrow = lane & 15, lq = lane >> 4;

    floatx4 acc[2][2] = {};

    const int srow = t >> 6;   // 0..3
    const int sk   = t & 63;   // k within tile (lane-contiguous -> coalesced)

    for (int k0 = 0; k0 < 512; k0 += 64) {
        __syncthreads();
        const bool kv = (k0 + sk) < D_;
        #pragma unroll
        for (int r = 0; r < 64; r += 4) {
            int row = r + srow;
            float av = kv ? A[(size_t)(m0 + row) * D_ + k0 + sk] : 0.f;
            float bv = kv ? W[(size_t)(n0 + row) * D_ + k0 + sk] : 0.f;
            int off = row * 128 + (((sk >> 3) ^ (row & 7)) * 16) + (sk & 7) * 2;
            *(unsigned short*)(Ab + off) = f2bf(av);
            *(unsigned short*)(Bb + off) = f2bf(bv);
        }
        __syncthreads();
        #pragma unroll
        for (int ks = 0; ks < 2; ++ks) {
            int kc = ks * 4 + lq;
            I4S8 af[2], bf[2];
            #pragma unroll
            for (int i = 0; i < 2; ++i) {
                af[i].i4 = *(const int4*)(Ab + sw_off(wm + i * 16 + lrow, kc));
                bf[i].i4 = *(const int4*)(Bb + sw_off(wn + i * 16 + lrow, kc));
            }
            #pragma unroll
            for (int i = 0; i < 2; ++i)
                #pragma unroll
                for (int j = 0; j < 2; ++j)
                    acc[i][j] = __builtin_amdgcn_mfma_f32_16x16x32_bf16(
                        af[i].s8, bf[j].s8, acc[i][j], 0, 0, 0);
        }
    }

    #pragma unroll
    for (int i = 0; i < 2; ++i) {
        #pragma unroll
        for (int j = 0; j < 2; ++j) {
            int n = n0 + wn + j * 16 + lrow;
            float bsv = bias[n];
            #pragma unroll
            for (int r = 0; r < 4; ++r) {
                int m = m0 + wm + i * 16 + lq * 4 + r;
                float v = acc[i][j][r] + bsv;
                v = v > 0.f ? v : 0.f;
                Hout[(size_t)m * H_ + n] = __float2bfloat16(v);
            }
        }
    }
}

// ===== GEMM2 (MFMA, split-K=8, deterministic): part[z] = h @ w2^T slice =====
// h [256][5120] bf16, w2 [511][5120] fp32. part [8][256][511] fp32 in ws.
__global__ __launch_bounds__(256) void gemm2_mfma(
    const __hip_bfloat16* __restrict__ Hm, const float* __restrict__ W,
    float* __restrict__ part)
{
    __shared__ char lds[16384];
    char* Ab = lds;
    char* Bb = lds + 8192;
    const int t = threadIdx.x;
    const int n0 = blockIdx.x * 64;
    const int m0 = blockIdx.y * 64;
    const int kbeg = blockIdx.z * 640;
    const int lane = t & 63, wave = t >> 6;
    const int wm = (wave & 1) * 32, wn = (wave >> 1) * 32;
    const int lrow = lane & 15, lq = lane >> 4;

    floatx4 acc[2][2] = {};

    const int ra_ = t >> 3;   // 0..31 rows (A)
    const int ca_ = t & 7;    // chunk 0..7
    const int rw_ = t >> 4;   // 0..15 rows (W)
    const int f4_ = t & 15;   // float4 index 0..15

    for (int k0 = 0; k0 < 640; k0 += 64) {
        __syncthreads();
        // A tile: 64 rows x 8 chunks of 8 bf16 (16B aligned dwordx4 loads)
        #pragma unroll
        for (int q = 0; q < 2; ++q) {
            int row = ra_ + 32 * q;
            int4 raw = *(const int4*)(Hm + (size_t)(m0 + row) * H_ + kbeg + k0 + ca_ * 8);
            *(int4*)(Ab + sw_off(row, ca_)) = raw;
        }
        // W tile: 64 rows x 16 float4 (aligned), convert to bf16, 8B writes
        #pragma unroll
        for (int q = 0; q < 4; ++q) {
            int row = rw_ + 16 * q;
            int n = n0 + row;
            float4 fv = make_float4(0.f, 0.f, 0.f, 0.f);
            if (n < D_) fv = *(const float4*)(W + (size_t)n * H_ + kbeg + k0 + f4_ * 4);
            unsigned int lo = (unsigned)f2bf(fv.x) | ((unsigned)f2bf(fv.y) << 16);
            unsigned int hi = (unsigned)f2bf(fv.z) | ((unsigned)f2bf(fv.w) << 16);
            int2 w8; w8.x = (int)lo; w8.y = (int)hi;
            int off = row * 128 + ((((f4_ >> 1) ^ (row & 7))) * 16) + (f4_ & 1) * 8;
            *(int2*)(Bb + off) = w8;
        }
        __syncthreads();
        #pragma unroll
        for (int ks = 0; ks < 2; ++ks) {
            int kc = ks * 4 + lq;
            I4S8 af[2], bf[2];
            #pragma unroll
            for (int i = 0; i < 2; ++i) {
                af[i].i4 = *(const int4*)(Ab + sw_off(wm + i * 16 + lrow, kc));
                bf[i].i4 = *(const int4*)(Bb + sw_off(wn + i * 16 + lrow, kc));
            }
            #pragma unroll
            for (int i = 0; i < 2; ++i)
                #pragma unroll
                for (int j = 0; j < 2; ++j)
                    acc[i][j] = __builtin_amdgcn_mfma_f32_16x16x32_bf16(
                        af[i].s8, bf[j].s8, acc[i][j], 0, 0, 0);
        }
    }

    float* Cp = part + (size_t)blockIdx.z * (B_ * D_);
    #pragma unroll
    for (int i = 0; i < 2; ++i) {
        #pragma unroll
        for (int j = 0; j < 2; ++j) {
            int n = n0 + wn + j * 16 + lrow;
            if (n < D_) {
                #pragma unroll
                for (int r = 0; r < 4; ++r) {
                    int m = m0 + wm + i * 16 + lq * 4 + r;
                    Cp[(size_t)m * D_ + n] = acc[i][j][r];
                }
            }
        }
    }
}

// ====== quad + final fused: row-sweep BW read of inv_Theta_11, then output ======
// 1024 threads = 16 waves; wave w handles rows w, w+16, ... Division-free.
__global__ __launch_bounds__(1024) void quad_final(
    const float* __restrict__ Mmat, const float* __restrict__ part,
    const float* __restrict__ b2,
    const float* __restrict__ stw1, const float* __restrict__ stb1,
    const float* __restrict__ stw2, const float* __restrict__ stb2,
    float* __restrict__ out)
{
    __shared__ float p[512];
    __shared__ float red[16];
    __shared__ float qsh;
    const int b = blockIdx.x;
    const int t = threadIdx.x;
    const int lane = t & 63, wv = t >> 6;

    // p = phi + b2 = sum of split-K partials + b2
    if (t < D_) {
        float s = b2[t];
        #pragma unroll
        for (int z = 0; z < 8; ++z)
            s += part[(size_t)z * (B_ * D_) + (size_t)b * D_ + t];
        p[t] = s;
    }
    __syncthreads();

    const float* Mb = Mmat + (size_t)b * NTOT;
    float acc = 0.f;

    for (int i = wv; i < D_; i += 16) {
        const float* row = Mb + (size_t)i * D_;
        // element misalignment of row start: (b*NTOT + i*D_) mod 4 = (b + 3i) mod 4
        const int mis = (b + 3 * i) & 3;
        const int headN = (4 - mis) & 3;
        const int nv = (D_ - headN) >> 2;   // number of aligned float4s
        float s = 0.f;
        if (lane < headN) s += row[lane] * p[lane];
        for (int v = lane; v < nv; v += 64) {
            int c = headN + v * 4;
            float4 m4 = *(const float4*)(row + c);   // 16B aligned by construction
            s += m4.x * p[c] + m4.y * p[c + 1] + m4.z * p[c + 2] + m4.w * p[c + 3];
        }
        int tb = headN + (nv << 2);
        if (lane < D_ - tb) s += row[tb + lane] * p[tb + lane];
        acc += s * p[i];   // p[i] wave-uniform -> LDS broadcast
    }

    #pragma unroll
    for (int off = 32; off > 0; off >>= 1) acc += __shfl_down(acc, off, 64);
    if (lane == 0) red[wv] = acc;
    __syncthreads();
    if (t == 0) {
        float s = 0.f;
        #pragma unroll
        for (int w = 0; w < 16; ++w) s += red[w];
        qsh = s;
    }
    __syncthreads();

    if (t < D_) {
        const float q = qsh;
        float x = p[t] / sqrtf(q);   // zeta = 1
        float lam = stb2[0];
        #pragma unroll
        for (int k = 0; k < 5; ++k) {
            float g = x * stw1[k] + stb1[k];
            g = g > 0.f ? g : 0.f;
            lam += g * stw2[k];
        }
        lam = fabsf(lam) * 0.1f;
        float ax = fabsf(x) - lam;
        ax = ax > 0.f ? ax : 0.f;
        float sgn = (x > 0.f) ? 1.f : ((x < 0.f) ? -1.f : 0.f);
        out[(size_t)b * D_ + t] = sgn * ax;
    }
}

extern "C" void kernel_launch(void* const* d_in, const int* in_sizes, int n_in,
                              void* d_out, int out_size, void* d_ws, size_t ws_size,
                              hipStream_t stream)
{
    const float* theta = (const float*)d_in[0];   // [B, D]
    const float* invT  = (const float*)d_in[3];   // [B, D, D]
    const float* w1    = (const float*)d_in[6];   // [H, D]
    const float* b1    = (const float*)d_in[7];   // [H]
    const float* w2    = (const float*)d_in[8];   // [D, H]
    const float* b2    = (const float*)d_in[9];   // [D]
    const float* stw1  = (const float*)d_in[10];  // [5]
    const float* stb1  = (const float*)d_in[11];  // [5]
    const float* stw2  = (const float*)d_in[12];  // [5]
    const float* stb2  = (const float*)d_in[13];  // [1]
    float* out = (float*)d_out;

    // ws layout: h (bf16, 2,621,440 B) | part (8*256*511 fp32, 4,186,112 B)
    __hip_bfloat16* h = (__hip_bfloat16*)d_ws;
    float* part = (float*)((char*)d_ws + (size_t)B_ * H_ * 2);

    // h = relu(theta @ w1^T + b1): M=256, N=5120(80 tiles), K=511->512
    gemm1_mfma<<<dim3(80, 4), 256, 0, stream>>>(theta, w1, b1, h);

    // part[z] = h @ w2^T (K-slice z): M=256, N=511(8 tiles), K=5120, split-K=8
    gemm2_mfma<<<dim3(8, 4, 8), 256, 0, stream>>>(h, w2, part);

    // p = sum(part)+b2; quad = p^T invT p; normalize + st-MLP + soft-threshold
    quad_final<<<B_, 1024, 0, stream>>>(invT, part, b2, stw1, stb1, stw2, stb2, out);
}